// Round 5
// baseline (126.150 us; speedup 1.0000x reference)
//
#include <hip/hip_runtime.h>
#include <math.h>

// ---------------- workspace layout ----------------
// CG dense: 729 floats at ws_f[0..728]
#define NF4 32   // 128 floats = 32 float4 per (n, channel)

typedef float f4 __attribute__((ext_vector_type(4)));  // clang vector: nontemporal-builtin OK

__device__ inline int deg_of(int A){ return (A==0) ? 0 : (A<4 ? 1 : 2); }

__device__ inline double factd(int n){
  double r = 1.0;
  for (int i = 2; i <= n; ++i) r *= (double)i;
  return r;
}

__device__ double cg_cplx(int l1,int m1,int l2,int m2,int l3,int m3){
  if (m1 + m2 != m3) return 0.0;
  if (l3 < abs(l1-l2) || l3 > l1+l2) return 0.0;
  double pref = (double)(2*l3+1) * factd(l1+l2-l3)*factd(l1-l2+l3)*factd(-l1+l2+l3)
                / factd(l1+l2+l3+1);
  pref *= factd(l3+m3)*factd(l3-m3)*factd(l1-m1)*factd(l1+m1)*factd(l2-m2)*factd(l2+m2);
  double s = 0.0;
  int k0 = max(0, max(l2-l3-m1, l1-l3+m2));
  int k1 = min(l1+l2-l3, min(l1-m1, l2+m2));
  for (int k = k0; k <= k1; ++k){
    double d = factd(k)*factd(l1+l2-l3-k)*factd(l1-m1-k)*factd(l2+m2-k)
               *factd(l3-l2+m1+k)*factd(l3-l1-m2+k);
    s += ((k & 1) ? -1.0 : 1.0) / d;
  }
  return sqrt(pref) * s;
}

// real<-complex change-of-basis entry U[l](row i, col m). Purely real or imag.
__device__ inline void u_ent(int l, int i, int m, double* re, double* im){
  *re = 0.0; *im = 0.0;
  const double s = 0.70710678118654752440;
  int mi = i - l;
  if (mi == 0){ if (m == 0) *re = 1.0; return; }
  if (mi > 0){
    if (m == mi)       *re = ((mi & 1) ? -1.0 : 1.0) * s;
    else if (m == -mi) *re = s;
    return;
  }
  int mp = -mi;
  if (m == mi)      *im = s;                            // column -mp
  else if (m == mp) *im = -((mp & 1) ? -1.0 : 1.0) * s; // column +mp
}

// one thread per (A,B,C) element of the 9x9x9 real CG tensor
__global__ void cg_kernel(float* __restrict__ ws_f){
  int tid = blockIdx.x * blockDim.x + threadIdx.x;
  if (tid >= 729) return;
  int A = tid / 81, B = (tid / 9) % 9, C = tid % 9;
  int l1 = deg_of(A), i = A - l1*l1;
  int l2 = deg_of(B), j = B - l2*l2;
  int l3 = deg_of(C), k = C - l3*l3;
  double out = 0.0;
  if (l3 >= abs(l1-l2) && l3 <= l1+l2){
    int mi = i - l1, mj = j - l2;
    int alist[2]; int na = (mi == 0) ? 1 : 2; alist[0] = mi; alist[1] = -mi;
    int blist[2]; int nb = (mj == 0) ? 1 : 2; blist[0] = mj; blist[1] = -mj;
    double tr = 0.0, ti = 0.0;
    for (int ai = 0; ai < na; ++ai){
      for (int bi = 0; bi < nb; ++bi){
        int a = alist[ai], b = blist[bi];
        int c = a + b;
        if (abs(c) > l3) continue;
        double u3r, u3i; u_ent(l3, k, c, &u3r, &u3i);
        if (u3r == 0.0 && u3i == 0.0) continue;
        double cgv = cg_cplx(l1, a, l2, b, l3, c);
        if (cgv == 0.0) continue;
        double u1r, u1i; u_ent(l1, i, a, &u1r, &u1i);
        double u2r, u2i; u_ent(l2, j, b, &u2r, &u2i);
        double pr = u1r*u2r - u1i*u2i;
        double pi = u1r*u2i + u1i*u2r;
        // multiply by conj(u3)
        double qr = pr*u3r + pi*u3i;
        double qi = pi*u3r - pr*u3i;
        tr += qr * cgv; ti += qi * cgv;
      }
    }
    out = (((l1+l2+l3) & 1) == 0) ? tr : ti;
  }
  ws_f[A*81 + B*9 + C] = (float)out;
}

// ---------------- main tensor-product kernel ----------------
// Fully compile-time-unrolled sparse coupling (selection rules give the exact
// support; values come from the device-computed cg table at compile-time-
// constant offsets -> scalar loads). All x/y/acc indices compile-time ->
// pure registers. float4 (16B/lane) nontemporal streams for x, y, out.
// __launch_bounds__(256,4): cap VGPR at 128 -> 4 waves/SIMD for latency hiding.

__device__ __forceinline__ void fma4s(f4& s, float v, const f4& a, const f4& b){
  s += v * a * b;
}

template<int l1,int l2,int l3,int r>
__device__ __forceinline__ void do_path(const float* __restrict__ cg,
    const f4* __restrict__ K4, int fi,
    const f4* xv, const f4* yv, f4* acc){
  f4 S[2*l3+1];
  #pragma unroll
  for (int k = 0; k < 2*l3+1; ++k) S[k] = (f4)0.f;
  #pragma unroll
  for (int i = 0; i < 2*l1+1; ++i){
    #pragma unroll
    for (int j = 0; j < 2*l2+1; ++j){
      const int m1 = i - l1, m2 = j - l2;
      const int mu1 = m1 < 0 ? -m1 : m1;
      const int mu2 = m2 < 0 ? -m2 : m2;
      const int s1 = (m1 < 0) ? 1 : 0, s2 = (m2 < 0) ? 1 : 0;
      const int s3 = (((l1+l2+l3) & 1) ? 1 : 0) ^ s1 ^ s2;
      #pragma unroll
      for (int t = 0; t < 2; ++t){
        const int lo  = (mu1 > mu2) ? (mu1 - mu2) : (mu2 - mu1);
        const int mu3 = t ? lo : (mu1 + mu2);
        if (t && lo == mu1 + mu2) continue;   // dedupe when a mu is 0
        if (mu3 > l3) continue;
        if (s3 && mu3 == 0) continue;         // no sin-type m3=0 row
        const int k = (s3 ? -mu3 : mu3) + l3;
        const int A = l1*l1 + i, B = l2*l2 + j, C = l3*l3 + k;
        const float v = cg[A*81 + B*9 + C];
        fma4s(S[k], v, xv[A], yv[B]);
      }
    }
  }
  const int koff = ((l1*3 + l2)*2 + r)*3 + l3;
  const f4 kv = K4[koff*NF4 + fi];
  #pragma unroll
  for (int k = 0; k < 2*l3+1; ++k) acc[k] += kv * S[k];
}

__global__ __launch_bounds__(256, 4) void tp_main(
    const float* __restrict__ xg, const float* __restrict__ yg,
    const float* __restrict__ Kg, float* __restrict__ outg,
    const float* __restrict__ cg){
  const int tid = threadIdx.x;
  const int fi  = tid & 31;            // float4 lane within feature dim
  const int n   = blockIdx.x * 8 + (tid >> 5);

  const f4* x4 = (const f4*)xg + (size_t)n * 9 * NF4 + fi;
  const f4* y4 = (const f4*)yg + (size_t)n * 9 * NF4 + fi;
  const f4* K4 = (const f4*)Kg;
  f4* out4 = (f4*)outg + (size_t)n * 18 * NF4 + fi;

  f4 xv[9], yv[9];
  #pragma unroll
  for (int a = 0; a < 9; ++a){
    xv[a] = __builtin_nontemporal_load(&x4[a*NF4]);
    yv[a] = __builtin_nontemporal_load(&y4[a*NF4]);
  }

  f4 acc[5];
  const f4 z4 = (f4)0.f;

  // ---- group (r=0, l3=0): paths (0,0),(1,1),(2,2) -> channel 0
  acc[0] = z4;
  do_path<0,0,0,0>(cg, K4, fi, xv, yv, acc);
  do_path<1,1,0,0>(cg, K4, fi, xv, yv, acc);
  do_path<2,2,0,0>(cg, K4, fi, xv, yv, acc);
  __builtin_nontemporal_store(acc[0], &out4[0*NF4]);

  // ---- group (r=0, l3=1): paths (1,1),(2,2) -> channels 1..3
  #pragma unroll
  for (int k = 0; k < 3; ++k) acc[k] = z4;
  do_path<1,1,1,0>(cg, K4, fi, xv, yv, acc);
  do_path<2,2,1,0>(cg, K4, fi, xv, yv, acc);
  #pragma unroll
  for (int k = 0; k < 3; ++k) __builtin_nontemporal_store(acc[k], &out4[(1+k)*NF4]);

  // ---- group (r=0, l3=2): paths (1,1),(2,2),(0,2),(2,0) -> channels 4..8
  #pragma unroll
  for (int k = 0; k < 5; ++k) acc[k] = z4;
  do_path<1,1,2,0>(cg, K4, fi, xv, yv, acc);
  do_path<2,2,2,0>(cg, K4, fi, xv, yv, acc);
  do_path<0,2,2,0>(cg, K4, fi, xv, yv, acc);
  do_path<2,0,2,0>(cg, K4, fi, xv, yv, acc);
  #pragma unroll
  for (int k = 0; k < 5; ++k) __builtin_nontemporal_store(acc[k], &out4[(4+k)*NF4]);

  // ---- group (r=1, l3=0): no parity-allowed paths -> channel 9 is zero
  __builtin_nontemporal_store(z4, &out4[9*NF4]);

  // ---- group (r=1, l3=1): paths (0,1),(1,0),(1,2),(2,1) -> channels 10..12
  #pragma unroll
  for (int k = 0; k < 3; ++k) acc[k] = z4;
  do_path<0,1,1,1>(cg, K4, fi, xv, yv, acc);
  do_path<1,0,1,1>(cg, K4, fi, xv, yv, acc);
  do_path<1,2,1,1>(cg, K4, fi, xv, yv, acc);
  do_path<2,1,1,1>(cg, K4, fi, xv, yv, acc);
  #pragma unroll
  for (int k = 0; k < 3; ++k) __builtin_nontemporal_store(acc[k], &out4[(10+k)*NF4]);

  // ---- group (r=1, l3=2): paths (1,2),(2,1) -> channels 13..17
  #pragma unroll
  for (int k = 0; k < 5; ++k) acc[k] = z4;
  do_path<1,2,2,1>(cg, K4, fi, xv, yv, acc);
  do_path<2,1,2,1>(cg, K4, fi, xv, yv, acc);
  #pragma unroll
  for (int k = 0; k < 5; ++k) __builtin_nontemporal_store(acc[k], &out4[(13+k)*NF4]);
}

extern "C" void kernel_launch(void* const* d_in, const int* in_sizes, int n_in,
                              void* d_out, int out_size, void* d_ws, size_t ws_size,
                              hipStream_t stream){
  const float* x = (const float*)d_in[0];   // (32768, 1, 9, 128)
  const float* y = (const float*)d_in[1];   // (32768, 1, 9, 128)
  const float* K = (const float*)d_in[2];   // (1,3,1,3,2,3,128)
  float* out = (float*)d_out;               // (32768, 2, 9, 128)
  float* ws_f = (float*)d_ws;

  hipLaunchKernelGGL(cg_kernel, dim3(1), dim3(768), 0, stream, ws_f);
  hipLaunchKernelGGL(tp_main, dim3(32768/8), dim3(256), 0, stream,
                     x, y, K, out, ws_f);
}